// Round 4
// baseline (248.584 us; speedup 1.0000x reference)
//
#include <hip/hip_runtime.h>
#include <hip/hip_bf16.h>
#include <cstdint>

// Problem constants (match reference)
#define B_SZ     256
#define D_DIM    2048
#define N_PROXY  16384
#define P_POS    4
#define K_SEL    54        // BG_KNN + P
#define TEMP_INV 20.0f     // 1/0.05

typedef __bf16 bf16_t;
typedef __bf16 bf16x4 __attribute__((ext_vector_type(4)));
typedef __bf16 bf16x8 __attribute__((ext_vector_type(8)));
typedef float  f32x4  __attribute__((ext_vector_type(4)));

// global_load_lds, width 16: per-lane global source, LDS dest = uniform base
// + lane*16 (linear).  No destination VGPR -> no compiler auto-waitcnt; all
// ordering is our explicit counted vmcnt.
__device__ __forceinline__ void gload_lds16(const void* g, void* l) {
    __builtin_amdgcn_global_load_lds(
        (const __attribute__((address_space(1))) void*)g,
        (__attribute__((address_space(3))) void*)l, 16, 0, 0);
}

// ---------------------------------------------------------------------------
// Kernel 0: F fp32 [256,2048] -> Fb bf16 in MFMA-A fragment-major layout.
// frag slot g = (mb*64 + kt)*64 + lane holds A[m=mb*16+(lane&15)]
// [k = kt*32 + (lane>>4)*8 + j], j=0..7.  Also zeroes the loss accumulator.
// ---------------------------------------------------------------------------
__global__ __launch_bounds__(256)
void conv_feat(const float* __restrict__ F, bf16_t* __restrict__ Fb,
               float* __restrict__ out) {
    int g    = blockIdx.x * 256 + threadIdx.x;   // 0..65535
    if (g == 0) *out = 0.0f;
    int lane = g & 63;
    int kt   = (g >> 6) & 63;
    int mb   = g >> 12;                          // 0..15
    int frow = lane & 15;
    int quad = (lane >> 4) & 3;
    const float* src = F + (size_t)(mb * 16 + frow) * D_DIM + kt * 32 + quad * 8;
    float4 lo = *(const float4*)src;
    float4 hi = *(const float4*)(src + 4);
    bf16x8 o = { (bf16_t)lo.x, (bf16_t)lo.y, (bf16_t)lo.z, (bf16_t)lo.w,
                 (bf16_t)hi.x, (bf16_t)hi.y, (bf16_t)hi.z, (bf16_t)hi.w };
    *(bf16x8*)(Fb + (size_t)g * 8) = o;
}

// ---------------------------------------------------------------------------
// Kernel 1: Sb = bf16((F @ em.T)/TEMP).  BM=256, BN=64, BK=32, grid 256,
// 512 threads (8 waves, wave w owns rows w*32..w*32+31, all 64 cols).
//
// v5 root cause (r1-r3 all ~2800 cyc/step, all pipes idle): vmcnt is an
// IN-ORDER counter, and the compiler's automatic wait for the A-fragment
// register loads (newest ops each step) retired the whole VMEM queue —
// including the E prefetch issued the same step.  Effective E depth was 1
// step => full HBM latency exposed every step, regardless of ring depth.
//
// Fix: E staging via global_load_lds (NO dest VGPR => no compiler auto-wait)
// into a quad-buffered fp32 LDS tile; ordering via explicit counted
// s_waitcnt vmcnt(6) per step (3 VMEM ops/wave/step, 2 steps in flight —
// the proven T3/T4 pattern).  A remains register-direct from L2-hot Fb,
// issued FIRST each step so its auto-wait retires only older ops.
// fp32->bf16 conversion moves to the read side (VALU, overlaps MFMA).
// LDS granule-XOR swizzle (g ^= row&7), applied as inverse pre-swizzle on
// the per-lane GLOBAL source (LDS dest linear) and re-applied on the read
// address: frag reads hit the b128 8-word/bank floor instead of 16-way
// conflicts.  MFMA fragment values identical to the verified kernel.
// ---------------------------------------------------------------------------
__global__ __launch_bounds__(512, 2)
void gemm_score(const bf16_t* __restrict__ Fb, const float* __restrict__ E,
                bf16_t* __restrict__ Sb) {
    const int tid  = threadIdx.x;
    const int bn   = blockIdx.x;          // 64-col n-stripe
    const int lane = tid & 63;
    const int w    = tid >> 6;            // wave 0..7
    const int frow = lane & 15;
    const int quad = (lane >> 4) & 3;

    // E tile buffers: 4 x [64 rows][32 fp32] = 4 x 8 KB, linear + granule XOR.
    __shared__ float Els[4][2048];

    // ---- staging addresses: wave w stages rows w*8..w*8+7 of the tile.
    // LDS dest (implicit) = base + lane*16 : row = w*8 + (lane>>3),
    // granule x = lane&7.  LDS[row][x] holds global granule x ^ (row&7);
    // row&7 == lane>>3, so source granule = (lane&7) ^ (lane>>3).
    const int   srow = w * 8 + (lane >> 3);
    const int   sgx  = (lane & 7) ^ (lane >> 3);
    const float* esrc = E + (size_t)(bn * 64 + srow) * D_DIM + sgx * 4;

    // ---- read-side constants: frag n, lane (frow, quad) needs
    // E row n*16+frow, fp32 cols quad*8..quad*8+7 = logical granules
    // 2q, 2q+1 -> LDS granules (2q)^(frow&7), (2q+1)^(frow&7).
    const int frbyte = frow * 128;                       // row byte offset
    const int x0 = (((quad << 1)    ) ^ (frow & 7)) << 4;
    const int x1 = x0 ^ 16;                              // (2q+1)^s == ((2q)^s)^1

    // A frag (m, kt) at Fb[((w*2+m)*64 + kt)*512 + lane*8]
    const bf16_t* Ab0 = Fb + (size_t)((w * 2 + 0) * 64) * 512 + lane * 8;
    const bf16_t* Ab1 = Fb + (size_t)((w * 2 + 1) * 64) * 512 + lane * 8;

    // Named accumulators [m in 0..1][n in 0..3]
    f32x4 c00 = {}, c01 = {}, c02 = {}, c03 = {};
    f32x4 c10 = {}, c11 = {}, c12 = {}, c13 = {};
    bf16x8 afA0, afA1, afB0, afB1;        // A double-buffer (named)

    // ---- prologue: stage E tiles 0..2, load A(0); wait tile 0; barrier ----
#pragma unroll
    for (int t = 0; t < 3; ++t)
        gload_lds16(esrc + (size_t)t * 32, (char*)Els + t * 8192 + w * 1024);
    afA0 = *(const bf16x8*)(Ab0);
    afA1 = *(const bf16x8*)(Ab1);
    afB0 = afA0; afB1 = afA1;             // init only; overwritten at step 0
    asm volatile("s_waitcnt vmcnt(2)" ::: "memory");   // robust to A/E order
    __builtin_amdgcn_s_barrier();
    asm volatile("" ::: "memory");

    // Per step K: [A(K+1) regs] [stage E tile (K+3)&63 -> buf (K+3)&3]
    // [read+cvt 4 E frags from buf K&3] [8 MFMA] [vmcnt(6)] [barrier].
    // vmcnt(6): 3 VMEM/wave/step, tile K+1's op has exactly 6 newer ops.
    // Tail wraps ((K+3)&63) keep the count uniform; the reloaded buffers
    // are never read again.
#define EFRAG(BGN, EB, NOFF)                                                   \
    bf16x8 BGN; {                                                              \
        f32x4 lo_ = *(const f32x4*)((EB) + (NOFF) + frbyte + x0);              \
        f32x4 hi_ = *(const f32x4*)((EB) + (NOFF) + frbyte + x1);              \
        BGN = (bf16x8){ (bf16_t)lo_[0], (bf16_t)lo_[1], (bf16_t)lo_[2],        \
                        (bf16_t)lo_[3], (bf16_t)hi_[0], (bf16_t)hi_[1],        \
                        (bf16_t)hi_[2], (bf16_t)hi_[3] };                      \
    }

#define STEP(K, AC0, AC1, AN0, AN1)                                            \
    {                                                                          \
        if ((K) + 1 < 64) {                                                    \
            AN0 = *(const bf16x8*)(Ab0 + ((K) + 1) * 512);                     \
            AN1 = *(const bf16x8*)(Ab1 + ((K) + 1) * 512);                     \
        }                                                                      \
        gload_lds16(esrc + (size_t)(((K) + 3) & 63) * 32,                      \
                    (char*)Els + (((K) + 3) & 3) * 8192 + w * 1024);           \
        const char* eb_ = (const char*)Els + ((K) & 3) * 8192;                 \
        EFRAG(bg0, eb_, 0)                                                     \
        EFRAG(bg1, eb_, 2048)                                                  \
        EFRAG(bg2, eb_, 4096)                                                  \
        EFRAG(bg3, eb_, 6144)                                                  \
        c00 = __builtin_amdgcn_mfma_f32_16x16x32_bf16(AC0, bg0, c00, 0, 0, 0); \
        c01 = __builtin_amdgcn_mfma_f32_16x16x32_bf16(AC0, bg1, c01, 0, 0, 0); \
        c02 = __builtin_amdgcn_mfma_f32_16x16x32_bf16(AC0, bg2, c02, 0, 0, 0); \
        c03 = __builtin_amdgcn_mfma_f32_16x16x32_bf16(AC0, bg3, c03, 0, 0, 0); \
        c10 = __builtin_amdgcn_mfma_f32_16x16x32_bf16(AC1, bg0, c10, 0, 0, 0); \
        c11 = __builtin_amdgcn_mfma_f32_16x16x32_bf16(AC1, bg1, c11, 0, 0, 0); \
        c12 = __builtin_amdgcn_mfma_f32_16x16x32_bf16(AC1, bg2, c12, 0, 0, 0); \
        c13 = __builtin_amdgcn_mfma_f32_16x16x32_bf16(AC1, bg3, c13, 0, 0, 0); \
        asm volatile("s_waitcnt vmcnt(6)" ::: "memory");                       \
        asm volatile("s_waitcnt lgkmcnt(0)" ::: "memory");                     \
        __builtin_amdgcn_s_barrier();                                          \
        asm volatile("" ::: "memory");                                         \
    }

    for (int k = 0; k < 64; k += 2) {
        STEP(k,     afA0, afA1, afB0, afB1)
        STEP(k + 1, afB0, afB1, afA0, afA1)
    }
#undef STEP
#undef EFRAG

    // ---- epilogue: C/D layout col=lane&15, row=quad*4+i; fold 1/TEMP ----
    {
        int gr0 = w * 32 + quad * 4;            // m=0 row base
        int gr1 = gr0 + 16;                     // m=1 row base
#define CWRITE(CV, GR, N)                                                      \
        {                                                                      \
            int gc = bn * 64 + (N) * 16 + frow;                                \
            _Pragma("unroll")                                                  \
            for (int i = 0; i < 4; ++i)                                        \
                Sb[(size_t)((GR) + i) * N_PROXY + gc] =                        \
                    (bf16_t)(CV[i] * TEMP_INV);                                \
        }
        CWRITE(c00, gr0, 0) CWRITE(c01, gr0, 1) CWRITE(c02, gr0, 2) CWRITE(c03, gr0, 3)
        CWRITE(c10, gr1, 0) CWRITE(c11, gr1, 1) CWRITE(c12, gr1, 2) CWRITE(c13, gr1, 3)
#undef CWRITE
    }
}

// ---------------------------------------------------------------------------
// Kernel 2: per-row top-K + log-softmax loss on bf16 scores.
// 512 threads/row, 32 keys/thread; 16-bit radix select with early exit.
// (unchanged this round — one structural change at a time)
// ---------------------------------------------------------------------------
__device__ __forceinline__ float key16_to_float(uint32_t k) {
    uint32_t bits16 = (k & 0x8000u) ? (k ^ 0x8000u) : ((~k) & 0xFFFFu);
    return __uint_as_float(bits16 << 16);
}

__device__ __forceinline__ int block_sum_i(int v, int tid, volatile int* rbuf) {
#pragma unroll
    for (int o = 32; o > 0; o >>= 1) v += __shfl_down(v, o, 64);
    __syncthreads();
    if ((tid & 63) == 0) rbuf[tid >> 6] = v;
    __syncthreads();
    int s = 0;
#pragma unroll
    for (int w = 0; w < 8; ++w) s += rbuf[w];
    return s;
}

__device__ __forceinline__ float block_sum_f(float v, int tid, volatile float* rbuf) {
#pragma unroll
    for (int o = 32; o > 0; o >>= 1) v += __shfl_down(v, o, 64);
    __syncthreads();
    if ((tid & 63) == 0) rbuf[tid >> 6] = v;
    __syncthreads();
    float s = 0.0f;
#pragma unroll
    for (int w = 0; w < 8; ++w) s += rbuf[w];
    return s;
}

__device__ __forceinline__ uint32_t block_max_u(uint32_t v, int tid,
                                                volatile uint32_t* rbuf) {
#pragma unroll
    for (int o = 32; o > 0; o >>= 1) {
        uint32_t w = __shfl_down(v, o, 64);
        v = (w > v) ? w : v;
    }
    __syncthreads();
    if ((tid & 63) == 0) rbuf[tid >> 6] = v;
    __syncthreads();
    uint32_t r = 0;
#pragma unroll
    for (int w = 0; w < 8; ++w) r = rbuf[w] > r ? rbuf[w] : r;
    return r;
}

__global__ __launch_bounds__(512)
void topk_loss(const bf16_t* __restrict__ S, const int* __restrict__ targets,
               const int* __restrict__ plabel, const int* __restrict__ ptable,
               float* __restrict__ out) {
    const int b    = blockIdx.x;
    const int tid  = threadIdx.x;
    const int lane = tid & 63;
    const int wave = tid >> 6;

    __shared__ int      sh_pos[4];
    __shared__ float    sh_pv[4];
    __shared__ int      sh_d;
    __shared__ int      rbuf_i[8];
    __shared__ float    rbuf_f[8];
    __shared__ uint32_t rbuf_u[8];
    __shared__ uint32_t cand_ls[64];
    __shared__ int      candcnt;
    __shared__ float    sh_numbg;

    const bf16_t* row = S + (size_t)b * N_PROXY;

    if (tid == 0) {
        int t  = targets[b];
        int py = plabel[t];
        int pos[4]; int d = 0;
        for (int j = 0; j < 4; ++j) {
            int p = ptable[py * 4 + j];
            bool dup = false;
            for (int i = 0; i < d; ++i) dup = dup || (pos[i] == p);
            if (!dup) pos[d++] = p;
        }
        sh_d = d;
        for (int j = 0; j < 4; ++j) sh_pos[j] = (j < d) ? pos[j] : -1;
        for (int j = 0; j < 4; ++j) sh_pv[j]  = (j < d) ? (float)row[pos[j]] : 0.0f;
        candcnt = 0;
    }
    __syncthreads();

    const int d  = sh_d;
    const int p0 = sh_pos[0], p1 = sh_pos[1], p2 = sh_pos[2], p3 = sh_pos[3];
    float pv[4];
#pragma unroll
    for (int j = 0; j < 4; ++j) pv[j] = sh_pv[j];

    // ---- 32 bf16 logits/thread as 16-bit sortable keys; positives -> 0 ----
    uint32_t keys[32];
#pragma unroll
    for (int j = 0; j < 4; ++j) {
        int g8 = j * 512 + tid;                     // 8-element granule
        ushort v[8];
        *(uint4*)v = *(const uint4*)(row + (size_t)g8 * 8);
#pragma unroll
        for (int q = 0; q < 8; ++q) {
            int idx = g8 * 8 + q;
            bool isp = (idx == p0) | (idx == p1) | (idx == p2) | (idx == p3);
            uint32_t bits = v[q];
            uint32_t key  = (bits & 0x8000u) ? ((~bits) & 0xFFFFu)
                                             : (bits | 0x8000u);
            keys[j * 8 + q] = isp ? 0u : key;
        }
    }

    const int need = K_SEL - d;              // backgrounds in the top-54 set

    // ---- 16-bit radix select with early exit ----
    uint32_t T = 0;
    for (int bit = 15; bit >= 0; --bit) {
        uint32_t cnd = T | (1u << bit);
        int c = 0;
#pragma unroll
        for (int j = 0; j < 32; ++j) c += (keys[j] >= cnd) ? 1 : 0;
        int ct = block_sum_i(c, tid, rbuf_i);
        if (ct >= need) {
            T = cnd;
            if (ct == need) break;           // selected set is exactly top-need
        }
    }
    const float vT = key16_to_float(T);

    // ---- stability max over backgrounds + positives ----
    uint32_t kmax = 0;
#pragma unroll
    for (int j = 0; j < 32; ++j) kmax = keys[j] > kmax ? keys[j] : kmax;
    kmax = block_max_u(kmax, tid, rbuf_u);
    float mx = key16_to_float(kmax);
    for (int j = 0; j < 4; ++j) if (j < d && pv[j] > mx) mx = pv[j];

    // ---- lse over selected set: strict-greater + exact tie fill + pos ----
    int c1 = 0; float se = 0.0f;
#pragma unroll
    for (int j = 0; j < 32; ++j) {
        if (keys[j] > T) { c1 += 1; se += __expf(key16_to_float(keys[j]) - mx); }
    }
    int   c1t = block_sum_i(c1, tid, rbuf_i);
    float set = block_sum_f(se, tid, rbuf_f);
    set += (float)(need - c1t) * __expf(vT - mx);
    for (int j = 0; j < 4; ++j) if (j < d) set += __expf(pv[j] - mx);
    const float lse = mx + logf(set);

    // ---- numerator: distinct positives + top (P-d) background values ----
    float num = 0.0f;
    for (int j = 0; j < 4; ++j) if (j < d) num += pv[j];
    if (d < P_POS) {
#pragma unroll
        for (int j = 0; j < 32; ++j) {
            if (keys[j] > T) {
                int p = atomicAdd(&candcnt, 1);
                cand_ls[p] = keys[j];
            }
        }
        __syncthreads();
        if (wave == 0) {
            const int cc = candcnt;
            uint32_t v = (lane < cc) ? cand_ls[lane] : T;   // pad with T (exact)
            float s = 0.0f;
            const int need2 = P_POS - d;                    // 1..3
            for (int it = 0; it < need2; ++it) {
                uint32_t m = v;
#pragma unroll
                for (int o = 32; o > 0; o >>= 1) {
                    uint32_t w = __shfl_xor(m, o, 64);
                    m = (w > m) ? w : m;
                }
                s += key16_to_float(m);
                unsigned long long msk = __ballot(v == m);
                int first = __ffsll(msk) - 1;
                if (lane == first) v = 0u;
            }
            if (lane == 0) sh_numbg = s;
        }
        __syncthreads();
        num += sh_numbg;
    }

    const float loss_b = lse - num * (1.0f / P_POS);
    if (tid == 0) atomicAdd(out, loss_b * (1.0f / B_SZ));
}

// ---------------------------------------------------------------------------
extern "C" void kernel_launch(void* const* d_in, const int* in_sizes, int n_in,
                              void* d_out, int out_size, void* d_ws, size_t ws_size,
                              hipStream_t stream) {
    const float* F       = (const float*)d_in[0];   // features [256,2048]
    const float* E       = (const float*)d_in[1];   // global_memory [16384,2048]
    const int*   targets = (const int*)d_in[2];     // [256]
    const int*   plabel  = (const int*)d_in[3];     // [32768]
    const int*   ptable  = (const int*)d_in[4];     // [4096,4]

    bf16_t* Fb = (bf16_t*)d_ws;                                     // 1 MB, frag-major
    bf16_t* Sb = (bf16_t*)((char*)d_ws + (size_t)B_SZ * D_DIM * 2); // 8 MB
    float*  out = (float*)d_out;

    // out is zeroed by conv_feat (stream-ordered before topk_loss's atomics)
    hipLaunchKernelGGL(conv_feat, dim3(256), dim3(256), 0, stream, F, Fb, out);
    hipLaunchKernelGGL(gemm_score, dim3(N_PROXY / 64), dim3(512), 0, stream,
                       Fb, E, Sb);
    hipLaunchKernelGGL(topk_loss, dim3(B_SZ), dim3(512), 0, stream,
                       Sb, targets, plabel, ptable, out);
}

// Round 5
// 231.813 us; speedup vs baseline: 1.0723x; 1.0723x over previous
//
#include <hip/hip_runtime.h>
#include <hip/hip_bf16.h>
#include <cstdint>

// Problem constants (match reference)
#define B_SZ     256
#define D_DIM    2048
#define N_PROXY  16384
#define P_POS    4
#define K_SEL    54        // BG_KNN + P
#define TEMP_INV 20.0f     // 1/0.05

typedef __bf16 bf16_t;
typedef __bf16 bf16x4 __attribute__((ext_vector_type(4)));
typedef __bf16 bf16x8 __attribute__((ext_vector_type(8)));
typedef float  f32x4  __attribute__((ext_vector_type(4)));

// global_load_lds, width 16: per-lane global source address; LDS dest =
// WAVE-UNIFORM base + lane*16 (hardware-applied).  No destination VGPR ->
// the compiler emits no automatic vmcnt wait for it; ordering is entirely
// our explicit counted s_waitcnt.
__device__ __forceinline__ void gload_lds16(const void* g, void* l) {
    __builtin_amdgcn_global_load_lds(
        (const __attribute__((address_space(1))) void*)g,
        (__attribute__((address_space(3))) void*)l, 16, 0, 0);
}

// ---------------------------------------------------------------------------
// Kernel 0: F fp32 [256,2048] -> Fb bf16 in MFMA-A fragment-major layout.
// frag slot g = (mb*64 + kt)*64 + lane holds A[m=mb*16+(lane&15)]
// [k = kt*32 + (lane>>4)*8 + j], j=0..7.  Also zeroes the loss accumulator.
// ---------------------------------------------------------------------------
__global__ __launch_bounds__(256)
void conv_feat(const float* __restrict__ F, bf16_t* __restrict__ Fb,
               float* __restrict__ out) {
    int g    = blockIdx.x * 256 + threadIdx.x;   // 0..65535
    if (g == 0) *out = 0.0f;
    int lane = g & 63;
    int kt   = (g >> 6) & 63;
    int mb   = g >> 12;                          // 0..15
    int frow = lane & 15;
    int quad = (lane >> 4) & 3;
    const float* src = F + (size_t)(mb * 16 + frow) * D_DIM + kt * 32 + quad * 8;
    float4 lo = *(const float4*)src;
    float4 hi = *(const float4*)(src + 4);
    bf16x8 o = { (bf16_t)lo.x, (bf16_t)lo.y, (bf16_t)lo.z, (bf16_t)lo.w,
                 (bf16_t)hi.x, (bf16_t)hi.y, (bf16_t)hi.z, (bf16_t)hi.w };
    *(bf16x8*)(Fb + (size_t)g * 8) = o;
}

// ---------------------------------------------------------------------------
// Kernel 1: Sb = bf16((F @ em.T)/TEMP).  BM=256, BN=64, BK=32, grid 256,
// 512 threads (8 waves; wave w computes rows w*32..w*32+31, all 64 cols).
//
// v6: ZERO register-destination global loads in the K-loop.  Rounds 0-4
// (four different schedules) all pinned at ~2900 cyc/step, all pipes <10%
// busy.  Common element: A-fragment REGISTER loads from Fb.  The compiler
// must auto-wait vmcnt for them before each step's MFMAs; vmcnt is in-order
// so that wait retires the whole queue, and Fb lines are continuously
// evicted from L2 by the E stream (16 MB/XCD streams through 4 MB L2), so
// each step's critical path became a far-memory A-load latency.
//
// Now BOTH operands are staged by global_load_lds (no dest VGPR -> no
// compiler wait exists in the loop): per K-step a 24 KB tile {A: 16 KB bf16
// frag-major from Fb, B: 8 KB fp32 from E}, 4-deep ring (96 KB LDS), issue
// distance 3, one counted s_waitcnt vmcnt(6) per step (3 ops/wave/step:
// guarantees tile K+1 landed; K+2, K+3 stay in flight across barriers).
// MFMA operands come exclusively from ds_read (~120 cyc, covered by 8
// waves).  B granule-XOR swizzle (gran ^= row&7) applied on the per-lane
// GLOBAL source (LDS dest linear, m173 rule) and re-applied on the read
// address.  fp32->bf16 cvt on the read side (VALU, overlaps MFMA).
// Fragment values identical to the verified kernel -> absmax stays 0.
// ---------------------------------------------------------------------------
__global__ __launch_bounds__(512)
void gemm_score(const bf16_t* __restrict__ Fb, const float* __restrict__ E,
                bf16_t* __restrict__ Sb) {
    const int tid  = threadIdx.x;
    const int bn   = blockIdx.x;          // 64-col n-stripe
    const int lane = tid & 63;
    const int w    = tid >> 6;            // wave 0..7
    const int frow = lane & 15;
    const int quad = (lane >> 4) & 3;

    // Ring of 4 tile buffers; each: A [16 frags][64 lanes][16B] = 16 KB,
    // then B [64 rows][8 grans][16B] = 8 KB.  96 KB total.
    __shared__ char tile[4][24576];

    // ---- staging sources (per-lane) ----
    // A: wave w stages frags mb = 2w, 2w+1.  Frag (mb,kt) is 1 KB contiguous
    // at byte (mb*64 + kt)*1024 + lane*16 of Fb.
    const char* aS0 = (const char*)Fb + ((w * 2 + 0) * 64) * 1024 + lane * 16;
    const char* aS1 = (const char*)Fb + ((w * 2 + 1) * 64) * 1024 + lane * 16;
    // B: wave w stages rows w*8..w*8+7.  LDS slot (row,gx) holds global
    // granule gx ^ (row&7); row&7 == lane>>3, so src granule = (lane&7)^(lane>>3).
    const char* bS = (const char*)E
                   + (size_t)(bn * 64 + w * 8 + (lane >> 3)) * (D_DIM * 4)
                   + (((lane & 7) ^ (lane >> 3)) * 16);

    // ---- staging LDS dests (wave-uniform; HW adds lane*16) ----
    const int aD0 = (w * 2 + 0) * 1024;
    const int aD1 = (w * 2 + 1) * 1024;
    const int bD  = 16384 + w * 1024;

    // ---- read-side constants ----
    // A frag m: byte (2w+m)*1024 + lane*16.
    // B frag n, lane(frow,quad): row n*16+frow, global granules 2q,2q+1 ->
    // LDS granules (2q)^(frow&7), +^1.
    const int aR0 = (w * 2 + 0) * 1024 + lane * 16;
    const int aR1 = (w * 2 + 1) * 1024 + lane * 16;
    const int x0  = (((quad << 1)) ^ (frow & 7)) << 4;
    const int x1  = x0 ^ 16;
    const int bR  = 16384 + frow * 128;   // + n*2048 + x0/x1

    f32x4 c00 = {}, c01 = {}, c02 = {}, c03 = {};
    f32x4 c10 = {}, c11 = {}, c12 = {}, c13 = {};

    // ---- prologue: stage tiles 0..2 (3 ops/tile/wave); tile 0 forced ----
#pragma unroll
    for (int t = 0; t < 3; ++t) {
        char* d = &tile[t][0];
        gload_lds16(aS0 + t * 1024, d + aD0);
        gload_lds16(aS1 + t * 1024, d + aD1);
        gload_lds16(bS  + t * 128,  d + bD);
    }
    asm volatile("s_waitcnt vmcnt(6)" ::: "memory");  // tile 0 landed
    __builtin_amdgcn_s_barrier();
    asm volatile("" ::: "memory");

    // Per step K: issue tile (K+3)&63 -> buf (K+3)&3, ds_read tile K&3,
    // cvt, 8 MFMA, vmcnt(6) [tile K+1 landed], barrier.  No register-dest
    // global loads anywhere in the loop.
#define STEP(K)                                                                \
    {                                                                          \
        {                                                                      \
            char* d_ = &tile[((K) + 3) & 3][0];                                \
            const int tt_ = ((K) + 3) & 63;                                    \
            gload_lds16(aS0 + tt_ * 1024, d_ + aD0);                           \
            gload_lds16(aS1 + tt_ * 1024, d_ + aD1);                           \
            gload_lds16(bS  + tt_ * 128,  d_ + bD);                            \
        }                                                                      \
        const char* s_ = &tile[(K) & 3][0];                                    \
        bf16x8 af0 = *(const bf16x8*)(s_ + aR0);                               \
        bf16x8 af1 = *(const bf16x8*)(s_ + aR1);                               \
        f32x4 l0 = *(const f32x4*)(s_ + bR + 0 * 2048 + x0);                   \
        f32x4 h0 = *(const f32x4*)(s_ + bR + 0 * 2048 + x1);                   \
        f32x4 l1 = *(const f32x4*)(s_ + bR + 1 * 2048 + x0);                   \
        f32x4 h1 = *(const f32x4*)(s_ + bR + 1 * 2048 + x1);                   \
        f32x4 l2 = *(const f32x4*)(s_ + bR + 2 * 2048 + x0);                   \
        f32x4 h2 = *(const f32x4*)(s_ + bR + 2 * 2048 + x1);                   \
        f32x4 l3 = *(const f32x4*)(s_ + bR + 3 * 2048 + x0);                   \
        f32x4 h3 = *(const f32x4*)(s_ + bR + 3 * 2048 + x1);                   \
        bf16x8 bg0 = { (bf16_t)l0[0], (bf16_t)l0[1], (bf16_t)l0[2],            \
                       (bf16_t)l0[3], (bf16_t)h0[0], (bf16_t)h0[1],            \
                       (bf16_t)h0[2], (bf16_t)h0[3] };                         \
        bf16x8 bg1 = { (bf16_t)l1[0], (bf16_t)l1[1], (bf16_t)l1[2],            \
                       (bf16_t)l1[3], (bf16_t)h1[0], (bf16_t)h1[1],            \
                       (bf16_t)h1[2], (bf16_t)h1[3] };                         \
        bf16x8 bg2 = { (bf16_t)l2[0], (bf16_t)l2[1], (bf16_t)l2[2],            \
                       (bf16_t)l2[3], (bf16_t)h2[0], (bf16_t)h2[1],            \
                       (bf16_t)h2[2], (bf16_t)h2[3] };                         \
        bf16x8 bg3 = { (bf16_t)l3[0], (bf16_t)l3[1], (bf16_t)l3[2],            \
                       (bf16_t)l3[3], (bf16_t)h3[0], (bf16_t)h3[1],            \
                       (bf16_t)h3[2], (bf16_t)h3[3] };                         \
        c00 = __builtin_amdgcn_mfma_f32_16x16x32_bf16(af0, bg0, c00, 0, 0, 0); \
        c01 = __builtin_amdgcn_mfma_f32_16x16x32_bf16(af0, bg1, c01, 0, 0, 0); \
        c02 = __builtin_amdgcn_mfma_f32_16x16x32_bf16(af0, bg2, c02, 0, 0, 0); \
        c03 = __builtin_amdgcn_mfma_f32_16x16x32_bf16(af0, bg3, c03, 0, 0, 0); \
        c10 = __builtin_amdgcn_mfma_f32_16x16x32_bf16(af1, bg0, c10, 0, 0, 0); \
        c11 = __builtin_amdgcn_mfma_f32_16x16x32_bf16(af1, bg1, c11, 0, 0, 0); \
        c12 = __builtin_amdgcn_mfma_f32_16x16x32_bf16(af1, bg2, c12, 0, 0, 0); \
        c13 = __builtin_amdgcn_mfma_f32_16x16x32_bf16(af1, bg3, c13, 0, 0, 0); \
        asm volatile("s_waitcnt vmcnt(6)" ::: "memory");                       \
        __builtin_amdgcn_s_barrier();                                          \
        asm volatile("" ::: "memory");                                         \
    }

    for (int k = 0; k < 64; k += 4) {
        STEP(k + 0)
        STEP(k + 1)
        STEP(k + 2)
        STEP(k + 3)
    }
#undef STEP

    // ---- epilogue: C/D layout col=lane&15, row=quad*4+i; fold 1/TEMP ----
    {
        int gr0 = w * 32 + quad * 4;            // m=0 row base
        int gr1 = gr0 + 16;                     // m=1 row base
#define CWRITE(CV, GR, N)                                                      \
        {                                                                      \
            int gc = bn * 64 + (N) * 16 + frow;                                \
            _Pragma("unroll")                                                  \
            for (int i = 0; i < 4; ++i)                                        \
                Sb[(size_t)((GR) + i) * N_PROXY + gc] =                        \
                    (bf16_t)(CV[i] * TEMP_INV);                                \
        }
        CWRITE(c00, gr0, 0) CWRITE(c01, gr0, 1) CWRITE(c02, gr0, 2) CWRITE(c03, gr0, 3)
        CWRITE(c10, gr1, 0) CWRITE(c11, gr1, 1) CWRITE(c12, gr1, 2) CWRITE(c13, gr1, 3)
#undef CWRITE
    }
}

// ---------------------------------------------------------------------------
// Kernel 2: per-row top-K + log-softmax loss on bf16 scores.
// 512 threads/row, 32 keys/thread; 16-bit radix select with early exit.
// (unchanged this round — one structural change at a time)
// ---------------------------------------------------------------------------
__device__ __forceinline__ float key16_to_float(uint32_t k) {
    uint32_t bits16 = (k & 0x8000u) ? (k ^ 0x8000u) : ((~k) & 0xFFFFu);
    return __uint_as_float(bits16 << 16);
}

__device__ __forceinline__ int block_sum_i(int v, int tid, volatile int* rbuf) {
#pragma unroll
    for (int o = 32; o > 0; o >>= 1) v += __shfl_down(v, o, 64);
    __syncthreads();
    if ((tid & 63) == 0) rbuf[tid >> 6] = v;
    __syncthreads();
    int s = 0;
#pragma unroll
    for (int w = 0; w < 8; ++w) s += rbuf[w];
    return s;
}

__device__ __forceinline__ float block_sum_f(float v, int tid, volatile float* rbuf) {
#pragma unroll
    for (int o = 32; o > 0; o >>= 1) v += __shfl_down(v, o, 64);
    __syncthreads();
    if ((tid & 63) == 0) rbuf[tid >> 6] = v;
    __syncthreads();
    float s = 0.0f;
#pragma unroll
    for (int w = 0; w < 8; ++w) s += rbuf[w];
    return s;
}

__device__ __forceinline__ uint32_t block_max_u(uint32_t v, int tid,
                                                volatile uint32_t* rbuf) {
#pragma unroll
    for (int o = 32; o > 0; o >>= 1) {
        uint32_t w = __shfl_down(v, o, 64);
        v = (w > v) ? w : v;
    }
    __syncthreads();
    if ((tid & 63) == 0) rbuf[tid >> 6] = v;
    __syncthreads();
    uint32_t r = 0;
#pragma unroll
    for (int w = 0; w < 8; ++w) r = rbuf[w] > r ? rbuf[w] : r;
    return r;
}

__global__ __launch_bounds__(512)
void topk_loss(const bf16_t* __restrict__ S, const int* __restrict__ targets,
               const int* __restrict__ plabel, const int* __restrict__ ptable,
               float* __restrict__ out) {
    const int b    = blockIdx.x;
    const int tid  = threadIdx.x;
    const int lane = tid & 63;
    const int wave = tid >> 6;

    __shared__ int      sh_pos[4];
    __shared__ float    sh_pv[4];
    __shared__ int      sh_d;
    __shared__ int      rbuf_i[8];
    __shared__ float    rbuf_f[8];
    __shared__ uint32_t rbuf_u[8];
    __shared__ uint32_t cand_ls[64];
    __shared__ int      candcnt;
    __shared__ float    sh_numbg;

    const bf16_t* row = S + (size_t)b * N_PROXY;

    if (tid == 0) {
        int t  = targets[b];
        int py = plabel[t];
        int pos[4]; int d = 0;
        for (int j = 0; j < 4; ++j) {
            int p = ptable[py * 4 + j];
            bool dup = false;
            for (int i = 0; i < d; ++i) dup = dup || (pos[i] == p);
            if (!dup) pos[d++] = p;
        }
        sh_d = d;
        for (int j = 0; j < 4; ++j) sh_pos[j] = (j < d) ? pos[j] : -1;
        for (int j = 0; j < 4; ++j) sh_pv[j]  = (j < d) ? (float)row[pos[j]] : 0.0f;
        candcnt = 0;
    }
    __syncthreads();

    const int d  = sh_d;
    const int p0 = sh_pos[0], p1 = sh_pos[1], p2 = sh_pos[2], p3 = sh_pos[3];
    float pv[4];
#pragma unroll
    for (int j = 0; j < 4; ++j) pv[j] = sh_pv[j];

    // ---- 32 bf16 logits/thread as 16-bit sortable keys; positives -> 0 ----
    uint32_t keys[32];
#pragma unroll
    for (int j = 0; j < 4; ++j) {
        int g8 = j * 512 + tid;                     // 8-element granule
        ushort v[8];
        *(uint4*)v = *(const uint4*)(row + (size_t)g8 * 8);
#pragma unroll
        for (int q = 0; q < 8; ++q) {
            int idx = g8 * 8 + q;
            bool isp = (idx == p0) | (idx == p1) | (idx == p2) | (idx == p3);
            uint32_t bits = v[q];
            uint32_t key  = (bits & 0x8000u) ? ((~bits) & 0xFFFFu)
                                             : (bits | 0x8000u);
            keys[j * 8 + q] = isp ? 0u : key;
        }
    }

    const int need = K_SEL - d;              // backgrounds in the top-54 set

    // ---- 16-bit radix select with early exit ----
    uint32_t T = 0;
    for (int bit = 15; bit >= 0; --bit) {
        uint32_t cnd = T | (1u << bit);
        int c = 0;
#pragma unroll
        for (int j = 0; j < 32; ++j) c += (keys[j] >= cnd) ? 1 : 0;
        int ct = block_sum_i(c, tid, rbuf_i);
        if (ct >= need) {
            T = cnd;
            if (ct == need) break;           // selected set is exactly top-need
        }
    }
    const float vT = key16_to_float(T);

    // ---- stability max over backgrounds + positives ----
    uint32_t kmax = 0;
#pragma unroll
    for (int j = 0; j < 32; ++j) kmax = keys[j] > kmax ? keys[j] : kmax;
    kmax = block_max_u(kmax, tid, rbuf_u);
    float mx = key16_to_float(kmax);
    for (int j = 0; j < 4; ++j) if (j < d && pv[j] > mx) mx = pv[j];

    // ---- lse over selected set: strict-greater + exact tie fill + pos ----
    int c1 = 0; float se = 0.0f;
#pragma unroll
    for (int j = 0; j < 32; ++j) {
        if (keys[j] > T) { c1 += 1; se += __expf(key16_to_float(keys[j]) - mx); }
    }
    int   c1t = block_sum_i(c1, tid, rbuf_i);
    float set = block_sum_f(se, tid, rbuf_f);
    set += (float)(need - c1t) * __expf(vT - mx);
    for (int j = 0; j < 4; ++j) if (j < d) set += __expf(pv[j] - mx);
    const float lse = mx + logf(set);

    // ---- numerator: distinct positives + top (P-d) background values ----
    float num = 0.0f;
    for (int j = 0; j < 4; ++j) if (j < d) num += pv[j];
    if (d < P_POS) {
#pragma unroll
        for (int j = 0; j < 32; ++j) {
            if (keys[j] > T) {
                int p = atomicAdd(&candcnt, 1);
                cand_ls[p] = keys[j];
            }
        }
        __syncthreads();
        if (wave == 0) {
            const int cc = candcnt;
            uint32_t v = (lane < cc) ? cand_ls[lane] : T;   // pad with T (exact)
            float s = 0.0f;
            const int need2 = P_POS - d;                    // 1..3
            for (int it = 0; it < need2; ++it) {
                uint32_t m = v;
#pragma unroll
                for (int o = 32; o > 0; o >>= 1) {
                    uint32_t w = __shfl_xor(m, o, 64);
                    m = (w > m) ? w : m;
                }
                s += key16_to_float(m);
                unsigned long long msk = __ballot(v == m);
                int first = __ffsll(msk) - 1;
                if (lane == first) v = 0u;
            }
            if (lane == 0) sh_numbg = s;
        }
        __syncthreads();
        num += sh_numbg;
    }

    const float loss_b = lse - num * (1.0f / P_POS);
    if (tid == 0) atomicAdd(out, loss_b * (1.0f / B_SZ));
}

// ---------------------------------------------------------------------------
extern "C" void kernel_launch(void* const* d_in, const int* in_sizes, int n_in,
                              void* d_out, int out_size, void* d_ws, size_t ws_size,
                              hipStream_t stream) {
    const float* F       = (const float*)d_in[0];   // features [256,2048]
    const float* E       = (const float*)d_in[1];   // global_memory [16384,2048]
    const int*   targets = (const int*)d_in[2];     // [256]
    const int*   plabel  = (const int*)d_in[3];     // [32768]
    const int*   ptable  = (const int*)d_in[4];     // [4096,4]

    bf16_t* Fb = (bf16_t*)d_ws;                                     // 1 MB, frag-major
    bf16_t* Sb = (bf16_t*)((char*)d_ws + (size_t)B_SZ * D_DIM * 2); // 8 MB
    float*  out = (float*)d_out;

    // out is zeroed by conv_feat (stream-ordered before topk_loss's atomics)
    hipLaunchKernelGGL(conv_feat, dim3(256), dim3(256), 0, stream, F, Fb, out);
    hipLaunchKernelGGL(gemm_score, dim3(N_PROXY / 64), dim3(512), 0, stream,
                       Fb, E, Sb);
    hipLaunchKernelGGL(topk_loss, dim3(B_SZ), dim3(512), 0, stream,
                       Sb, targets, plabel, ptable, out);
}